// Round 1
// baseline (226.599 us; speedup 1.0000x reference)
//
#include <hip/hip_runtime.h>
#include <hip/hip_bf16.h>
#include <math.h>

#define N 4096

// order-preserving float <-> uint encoding for atomicMax on floats
__device__ __forceinline__ unsigned encf(float x) {
    unsigned u = __float_as_uint(x);
    return (u & 0x80000000u) ? ~u : (u | 0x80000000u);
}
__device__ __forceinline__ float decf(unsigned e) {
    unsigned u = (e & 0x80000000u) ? (e & 0x7fffffffu) : ~e;
    return __uint_as_float(u);
}

// K1: bitonic sort preds ascending -> xs  (1 block, 1024 threads)
__global__ void k_sort_preds(const float* __restrict__ preds, float* __restrict__ xs) {
    __shared__ float v[N];
    int tid = threadIdx.x;
    for (int m = 0; m < 4; m++) v[tid + 1024 * m] = preds[tid + 1024 * m];
    __syncthreads();
    for (int k = 2; k <= N; k <<= 1) {
        for (int j = k >> 1; j > 0; j >>= 1) {
            for (int m = 0; m < 4; m++) {
                int i = tid + 1024 * m;
                int p = i ^ j;
                if (p > i) {
                    float a = v[i], b = v[p];
                    bool up = ((i & k) == 0);
                    if ((a > b) == up) { v[i] = b; v[p] = a; }
                }
            }
            __syncthreads();
        }
    }
    for (int m = 0; m < 4; m++) xs[tid + 1024 * m] = v[tid + 1024 * m];
}

// K2: y[i] = softmax_j(-(xs_i - preds_j)^2/tau) . target   (row max is exactly 0)
__global__ void k_softmax_mv(const float* __restrict__ preds, const float* __restrict__ target,
                             const float* __restrict__ xs, float* __restrict__ y) {
    __shared__ float sp[N];
    __shared__ float st[N];
    __shared__ float rz[4], rn[4];
    int tid = threadIdx.x; // 256
    for (int m = 0; m < 16; m++) {
        int idx = tid + 256 * m;
        sp[idx] = preds[idx];
        st[idx] = target[idx];
    }
    __syncthreads();
    int row0 = blockIdx.x * 8;
    for (int rr = 0; rr < 8; rr++) {
        int i = row0 + rr;
        float xv = xs[i];
        float Z = 0.f, Nm = 0.f;
        #pragma unroll 4
        for (int m = 0; m < 16; m++) {
            int jj = tid + 256 * m;
            float dx = xv - sp[jj];
            float e = __expf(-100.0f * dx * dx);
            Z += e;
            Nm += e * st[jj];
        }
        #pragma unroll
        for (int d = 32; d; d >>= 1) {
            Z += __shfl_down(Z, d);
            Nm += __shfl_down(Nm, d);
        }
        if ((tid & 63) == 0) { rz[tid >> 6] = Z; rn[tid >> 6] = Nm; }
        __syncthreads();
        if (tid == 0) {
            float Zt = rz[0] + rz[1] + rz[2] + rz[3];
            float Nt = rn[0] + rn[1] + rn[2] + rn[3];
            y[i] = Nt / Zt;
        }
        __syncthreads();
    }
}

// K3: descending-stable sort of (y, idx); s = y_desc*100; z[t] = (N-t) - s[t];
//     f64 cumsum cs[0..N]; init venc. (1 block, 1024 threads)
__global__ void k_prep(const float* __restrict__ y, float* __restrict__ s_out,
                       int* __restrict__ perm_out, double* __restrict__ cs,
                       unsigned* __restrict__ venc) {
    __shared__ float sv[N];
    __shared__ int si[N];
    __shared__ double red[1024];
    int tid = threadIdx.x;
    for (int m = 0; m < 4; m++) { int i = tid + 1024 * m; sv[i] = y[i]; si[i] = i; }
    __syncthreads();
    for (int k = 2; k <= N; k <<= 1) {
        for (int j = k >> 1; j > 0; j >>= 1) {
            for (int m = 0; m < 4; m++) {
                int i = tid + 1024 * m;
                int p = i ^ j;
                if (p > i) {
                    float av = sv[i], bv = sv[p];
                    int ai = si[i], bi = si[p];
                    bool before = (av > bv) || (av == bv && ai < bi); // descending, stable
                    bool up = ((i & k) == 0);
                    if (before != up) { sv[i] = bv; sv[p] = av; si[i] = bi; si[p] = ai; }
                }
            }
            __syncthreads();
        }
    }
    for (int m = 0; m < 4; m++) {
        int t = tid + 1024 * m;
        float s = sv[t] * 100.0f;
        s_out[t] = s;
        perm_out[t] = si[t];
        venc[t] = encf(-INFINITY);
    }
    // f64 cumsum of z[t] = (N - t) - s[t]
    double loc[4];
    double tot = 0.0;
    for (int e = 0; e < 4; e++) {
        int t = 4 * tid + e;
        double z = (double)(N - t) - (double)(sv[t] * 100.0f);
        tot += z;
        loc[e] = tot;
    }
    red[tid] = tot;
    __syncthreads();
    for (int off = 1; off < 1024; off <<= 1) {
        double x = red[tid];
        if (tid >= off) x += red[tid - off];
        __syncthreads();
        red[tid] = x;
        __syncthreads();
    }
    double offset = (tid > 0) ? red[tid - 1] : 0.0;
    for (int e = 0; e < 4; e++) cs[4 * tid + e + 1] = offset + loc[e];
    if (tid == 0) cs[0] = 0.0;
}

// K4: isotonic via min-max formula. Block g handles j in [16g, 16g+16):
//     per row j, suffix-min over k of mean(z[j..k]); column-max into Vloc;
//     merge to global via atomicMax on encoded floats.
__global__ void k_iso_scan(const double* __restrict__ cs, unsigned* __restrict__ venc) {
    __shared__ double scs[N + 1];
    __shared__ float Vloc[N];
    __shared__ float mArr[256];
    __shared__ float incl[256];
    int tid = threadIdx.x; // 256
    for (int m = 0; m < 17; m++) {
        int idx = tid + 256 * m;
        if (idx < N + 1) scs[idx] = cs[idx];
    }
    for (int m = 0; m < 16; m++) Vloc[tid + 256 * m] = -INFINITY;
    __syncthreads();
    int j0 = blockIdx.x * 16;
    int kbase = tid * 16;
    for (int jr = 0; jr < 16; jr++) {
        int j = j0 + jr;
        double csj = scs[j];
        float f[16], ls[16];
        #pragma unroll
        for (int e = 0; e < 16; e++) {
            int k = kbase + e;
            f[e] = (k >= j) ? (float)(scs[k + 1] - csj) / (float)(k - j + 1) : INFINITY;
        }
        ls[15] = f[15];
        #pragma unroll
        for (int e = 14; e >= 0; e--) ls[e] = fminf(f[e], ls[e + 1]);
        mArr[tid] = ls[0];
        __syncthreads();
        if (tid < 64) { // wave 0: inclusive suffix-min over the 256 chunk minima
            float a0 = mArr[4 * tid + 0], a1 = mArr[4 * tid + 1];
            float a2 = mArr[4 * tid + 2], a3 = mArr[4 * tid + 3];
            float s3 = a3;
            float s2 = fminf(a2, s3);
            float s1 = fminf(a1, s2);
            float s0 = fminf(a0, s1);
            float v = s0;
            #pragma unroll
            for (int d = 1; d < 64; d <<= 1) {
                float o = __shfl_down(v, d);
                if (tid + d < 64) v = fminf(v, o);
            }
            float after = __shfl_down(v, 1);
            if (tid == 63) after = INFINITY;
            incl[4 * tid + 0] = fminf(s0, after);
            incl[4 * tid + 1] = fminf(s1, after);
            incl[4 * tid + 2] = fminf(s2, after);
            incl[4 * tid + 3] = fminf(s3, after);
        }
        __syncthreads();
        float aft = (tid < 255) ? incl[tid + 1] : INFINITY;
        #pragma unroll
        for (int e = 0; e < 16; e++) {
            int i = kbase + e;
            if (i >= j) Vloc[i] = fmaxf(Vloc[i], fminf(ls[e], aft));
        }
        __syncthreads();
    }
    for (int m = 0; m < 16; m++) {
        int i = tid + 256 * m;
        if (i >= j0) atomicMax(&venc[i], encf(Vloc[i]));
    }
}

// K5: primal = s + iso; scatter r[perm[t]] = primal; sum |adjacent diffs|; emit out.
__global__ void k_finish(const unsigned* __restrict__ venc, const float* __restrict__ s,
                         const int* __restrict__ perm, float* __restrict__ out) {
    __shared__ float r[N];
    __shared__ double red[16];
    int tid = threadIdx.x; // 1024
    for (int m = 0; m < 4; m++) {
        int t = tid + 1024 * m;
        float u = decf(venc[t]);
        r[perm[t]] = s[t] + u;
    }
    __syncthreads();
    double acc = 0.0;
    for (int m = 0; m < 4; m++) {
        int d = tid + 1024 * m;
        if (d < N - 1) acc += fabs((double)r[d + 1] - (double)r[d]);
    }
    #pragma unroll
    for (int dd = 32; dd; dd >>= 1) acc += __shfl_down(acc, dd);
    if ((tid & 63) == 0) red[tid >> 6] = acc;
    __syncthreads();
    if (tid == 0) {
        double ds = 0.0;
        for (int w = 0; w < 16; w++) ds += red[w];
        double xi = 1.0 - 3.0 * ds / ((double)N * (double)N - 1.0);
        out[0] = (float)(-1.0 * xi); // loss = -WEIGHT * xi
        out[1] = (float)xi;
    }
}

extern "C" void kernel_launch(void* const* d_in, const int* in_sizes, int n_in,
                              void* d_out, int out_size, void* d_ws, size_t ws_size,
                              hipStream_t stream) {
    const float* preds  = (const float*)d_in[0];
    const float* target = (const float*)d_in[1];
    float* out = (float*)d_out;

    char* ws = (char*)d_ws;
    float*    xs   = (float*)(ws);            // 16384 B
    float*    y    = (float*)(ws + 16384);    // 16384 B
    float*    s    = (float*)(ws + 32768);    // 16384 B
    int*      perm = (int*)(ws + 49152);      // 16384 B
    unsigned* venc = (unsigned*)(ws + 65536); // 16384 B
    double*   cs   = (double*)(ws + 81920);   // 32776 B

    k_sort_preds<<<1, 1024, 0, stream>>>(preds, xs);
    k_softmax_mv<<<512, 256, 0, stream>>>(preds, target, xs, y);
    k_prep<<<1, 1024, 0, stream>>>(y, s, perm, cs, venc);
    k_iso_scan<<<256, 256, 0, stream>>>(cs, venc);
    k_finish<<<1, 1024, 0, stream>>>(venc, s, perm, out);
}

// Round 2
// 205.118 us; speedup vs baseline: 1.1047x; 1.1047x over previous
//
#include <hip/hip_runtime.h>
#include <hip/hip_bf16.h>
#include <math.h>

#define N 4096

// order-preserving float <-> uint encoding for atomicMax on floats
__device__ __forceinline__ unsigned encf(float x) {
    unsigned u = __float_as_uint(x);
    return (u & 0x80000000u) ? ~u : (u | 0x80000000u);
}
__device__ __forceinline__ float decf(unsigned e) {
    unsigned u = (e & 0x80000000u) ? (e & 0x7fffffffu) : ~e;
    return __uint_as_float(u);
}

// K1: ascending rank-sort of preds via counting. 256 blocks x 256 threads.
// Block b owns elements [16b, 16b+16); 16 j-slices of 256 each per element.
__global__ void k_rank_preds(const float* __restrict__ preds, float* __restrict__ xs) {
    __shared__ __align__(16) float sp[N];
    __shared__ int part[16][17];
    int tid = threadIdx.x;
    int b = blockIdx.x;
    for (int m = 0; m < 16; m++) sp[tid + 256 * m] = preds[tid + 256 * m];
    __syncthreads();
    int eloc = tid & 15;
    int slice = tid >> 4;
    int i = b * 16 + eloc;
    float v = sp[i];
    int cnt = 0;
    const float4* sp4 = (const float4*)sp;
    for (int it = 0; it < 64; it++) {
        int q = slice * 64 + ((it + slice) & 63); // stagger slices across banks
        float4 a = sp4[q];
        int j = q * 4;
        cnt += (a.x < v) || (a.x == v && (j + 0) < i);
        cnt += (a.y < v) || (a.y == v && (j + 1) < i);
        cnt += (a.z < v) || (a.z == v && (j + 2) < i);
        cnt += (a.w < v) || (a.w == v && (j + 3) < i);
    }
    part[eloc][slice] = cnt;
    __syncthreads();
    if (tid < 16) {
        int r = 0;
        #pragma unroll
        for (int s = 0; s < 16; s++) r += part[tid][s];
        xs[r] = sp[b * 16 + tid];
    }
}

// K2: y[i] = softmax_j(-(xs_i - preds_j)^2/tau) . target   (row max is exactly 0)
__global__ void k_softmax_mv(const float* __restrict__ preds, const float* __restrict__ target,
                             const float* __restrict__ xs, float* __restrict__ y) {
    __shared__ float sp[N];
    __shared__ float st[N];
    __shared__ float rz[4], rn[4];
    int tid = threadIdx.x; // 256
    for (int m = 0; m < 16; m++) {
        int idx = tid + 256 * m;
        sp[idx] = preds[idx];
        st[idx] = target[idx];
    }
    __syncthreads();
    int row0 = blockIdx.x * 8;
    for (int rr = 0; rr < 8; rr++) {
        int i = row0 + rr;
        float xv = xs[i];
        float Z = 0.f, Nm = 0.f;
        #pragma unroll 4
        for (int m = 0; m < 16; m++) {
            int jj = tid + 256 * m;
            float dx = xv - sp[jj];
            float e = __expf(-100.0f * dx * dx);
            Z += e;
            Nm += e * st[jj];
        }
        #pragma unroll
        for (int d = 32; d; d >>= 1) {
            Z += __shfl_down(Z, d);
            Nm += __shfl_down(Nm, d);
        }
        if ((tid & 63) == 0) { rz[tid >> 6] = Z; rn[tid >> 6] = Nm; }
        __syncthreads();
        if (tid == 0) {
            float Zt = rz[0] + rz[1] + rz[2] + rz[3];
            float Nt = rn[0] + rn[1] + rn[2] + rn[3];
            y[i] = Nt / Zt;
        }
        __syncthreads();
    }
}

// K3: descending stable rank-sort of y via counting; s[r]=y*100, perm[r]=i;
//     init venc. 256 blocks x 256 threads.
__global__ void k_rank_y(const float* __restrict__ y, float* __restrict__ s_out,
                         int* __restrict__ perm_out, unsigned* __restrict__ venc) {
    __shared__ __align__(16) float sy[N];
    __shared__ int part[16][17];
    int tid = threadIdx.x;
    int b = blockIdx.x;
    for (int m = 0; m < 16; m++) sy[tid + 256 * m] = y[tid + 256 * m];
    __syncthreads();
    int eloc = tid & 15;
    int slice = tid >> 4;
    int i = b * 16 + eloc;
    float v = sy[i];
    int cnt = 0;
    const float4* sy4 = (const float4*)sy;
    for (int it = 0; it < 64; it++) {
        int q = slice * 64 + ((it + slice) & 63);
        float4 a = sy4[q];
        int j = q * 4;
        cnt += (a.x > v) || (a.x == v && (j + 0) < i);
        cnt += (a.y > v) || (a.y == v && (j + 1) < i);
        cnt += (a.z > v) || (a.z == v && (j + 2) < i);
        cnt += (a.w > v) || (a.w == v && (j + 3) < i);
    }
    part[eloc][slice] = cnt;
    __syncthreads();
    if (tid < 16) {
        int r = 0;
        #pragma unroll
        for (int s = 0; s < 16; s++) r += part[tid][s];
        int i2 = b * 16 + tid;
        s_out[r] = sy[i2] * 100.0f;
        perm_out[r] = i2;
        venc[i2] = encf(-INFINITY);
    }
}

// K4: f64 cumsum of z[t] = (N-t) - s[t].  1 block x 256 threads, 16 elems each.
__global__ void k_cumsum(const float* __restrict__ s, double* __restrict__ cs) {
    __shared__ double wt[4];
    int tid = threadIdx.x;
    int lane = tid & 63, wid = tid >> 6;
    const float4* s4 = (const float4*)s;
    double loc[16];
    double tot = 0.0;
    #pragma unroll
    for (int q = 0; q < 4; q++) {
        float4 a = s4[tid * 4 + q];
        int t0 = tid * 16 + q * 4;
        tot += (double)(N - (t0 + 0)) - (double)a.x; loc[q * 4 + 0] = tot;
        tot += (double)(N - (t0 + 1)) - (double)a.y; loc[q * 4 + 1] = tot;
        tot += (double)(N - (t0 + 2)) - (double)a.z; loc[q * 4 + 2] = tot;
        tot += (double)(N - (t0 + 3)) - (double)a.w; loc[q * 4 + 3] = tot;
    }
    double w = tot;
    #pragma unroll
    for (int d = 1; d < 64; d <<= 1) {
        double o = __shfl_up(w, d);
        if (lane >= d) w += o;
    }
    if (lane == 63) wt[wid] = w;
    __syncthreads();
    double base = 0.0;
    for (int q = 0; q < 4; q++) if (q < wid) base += wt[q];
    double excl = base + (w - tot);
    #pragma unroll
    for (int e = 0; e < 16; e++) cs[tid * 16 + e + 1] = excl + loc[e];
    if (tid == 0) cs[0] = 0.0;
}

// K5: isotonic via min-max formula, register-resident cs chunk and Vloc,
// rcp instead of divide, 4 rows per barrier round (one wave scans each row).
__global__ void k_iso2(const double* __restrict__ cs, unsigned* __restrict__ venc) {
    __shared__ __align__(16) float mArr[4][256];
    __shared__ float incl[4][257];
    __shared__ double cj[16];
    int tid = threadIdx.x; // 256
    int j0 = blockIdx.x * 16;
    int kbase = tid * 16;
    if (tid < 16) cj[tid] = cs[j0 + tid];
    double csr[16];
    #pragma unroll
    for (int e = 0; e < 16; e++) csr[e] = cs[kbase + 1 + e];
    float vloc[16];
    #pragma unroll
    for (int e = 0; e < 16; e++) vloc[e] = -INFINITY;
    __syncthreads();
    float ls[4][16];
    for (int grp = 0; grp < 4; grp++) {
        #pragma unroll
        for (int rq = 0; rq < 4; rq++) {
            int j = j0 + grp * 4 + rq;
            double csj = cj[grp * 4 + rq];
            float run = INFINITY;
            #pragma unroll
            for (int e = 15; e >= 0; e--) {
                int k = kbase + e;
                float f;
                if (k >= j) {
                    float len = (float)(k - j + 1);
                    f = (float)(csr[e] - csj) * __builtin_amdgcn_rcpf(len);
                } else {
                    f = INFINITY;
                }
                run = fminf(f, run);
                ls[rq][e] = run;
            }
            mArr[rq][tid] = run;
        }
        __syncthreads();
        {
            int w = tid >> 6, l = tid & 63;
            float4 xv = ((const float4*)mArr[w])[l];
            float s3 = xv.w;
            float s2 = fminf(xv.z, s3);
            float s1 = fminf(xv.y, s2);
            float s0 = fminf(xv.x, s1);
            float t = s0;
            #pragma unroll
            for (int d = 1; d < 64; d <<= 1) {
                float o = __shfl_down(t, d);
                if (l + d < 64) t = fminf(t, o);
            }
            float after = __shfl_down(t, 1);
            if (l == 63) after = INFINITY;
            incl[w][4 * l + 0] = fminf(s0, after);
            incl[w][4 * l + 1] = fminf(s1, after);
            incl[w][4 * l + 2] = fminf(s2, after);
            incl[w][4 * l + 3] = fminf(s3, after);
            if (l == 0) incl[w][256] = INFINITY;
        }
        __syncthreads();
        #pragma unroll
        for (int rq = 0; rq < 4; rq++) {
            int j = j0 + grp * 4 + rq;
            float aft = incl[rq][tid + 1];
            #pragma unroll
            for (int e = 0; e < 16; e++) {
                int i = kbase + e;
                float sv = fminf(ls[rq][e], aft);
                if (i >= j) vloc[e] = fmaxf(vloc[e], sv);
            }
        }
        __syncthreads();
    }
    if (kbase + 15 >= j0) {
        #pragma unroll
        for (int e = 0; e < 16; e++) {
            int i = kbase + e;
            if (i >= j0) atomicMax(&venc[i], encf(vloc[e]));
        }
    }
}

// K6: primal = s + iso; scatter r[perm[t]] = primal; sum |adjacent diffs|; emit out.
__global__ void k_finish(const unsigned* __restrict__ venc, const float* __restrict__ s,
                         const int* __restrict__ perm, float* __restrict__ out) {
    __shared__ float r[N];
    __shared__ double red[16];
    int tid = threadIdx.x; // 1024
    for (int m = 0; m < 4; m++) {
        int t = tid + 1024 * m;
        float u = decf(venc[t]);
        r[perm[t]] = s[t] + u;
    }
    __syncthreads();
    double acc = 0.0;
    for (int m = 0; m < 4; m++) {
        int d = tid + 1024 * m;
        if (d < N - 1) acc += fabs((double)r[d + 1] - (double)r[d]);
    }
    #pragma unroll
    for (int dd = 32; dd; dd >>= 1) acc += __shfl_down(acc, dd);
    if ((tid & 63) == 0) red[tid >> 6] = acc;
    __syncthreads();
    if (tid == 0) {
        double ds = 0.0;
        for (int w = 0; w < 16; w++) ds += red[w];
        double xi = 1.0 - 3.0 * ds / ((double)N * (double)N - 1.0);
        out[0] = (float)(-1.0 * xi); // loss = -WEIGHT * xi
        out[1] = (float)xi;
    }
}

extern "C" void kernel_launch(void* const* d_in, const int* in_sizes, int n_in,
                              void* d_out, int out_size, void* d_ws, size_t ws_size,
                              hipStream_t stream) {
    const float* preds  = (const float*)d_in[0];
    const float* target = (const float*)d_in[1];
    float* out = (float*)d_out;

    char* ws = (char*)d_ws;
    float*    xs   = (float*)(ws);            // 16384 B
    float*    y    = (float*)(ws + 16384);    // 16384 B
    float*    s    = (float*)(ws + 32768);    // 16384 B
    int*      perm = (int*)(ws + 49152);      // 16384 B
    unsigned* venc = (unsigned*)(ws + 65536); // 16384 B
    double*   cs   = (double*)(ws + 81920);   // 32776 B

    k_rank_preds<<<256, 256, 0, stream>>>(preds, xs);
    k_softmax_mv<<<512, 256, 0, stream>>>(preds, target, xs, y);
    k_rank_y<<<256, 256, 0, stream>>>(y, s, perm, venc);
    k_cumsum<<<1, 256, 0, stream>>>(s, cs);
    k_iso2<<<256, 256, 0, stream>>>(cs, venc);
    k_finish<<<1, 1024, 0, stream>>>(venc, s, perm, out);
}

// Round 3
// 126.242 us; speedup vs baseline: 1.7950x; 1.6248x over previous
//
#include <hip/hip_runtime.h>
#include <hip/hip_bf16.h>
#include <math.h>

#define N 4096

// order-preserving float <-> uint encoding for atomicMax on floats (fallback path)
__device__ __forceinline__ unsigned encf(float x) {
    unsigned u = __float_as_uint(x);
    return (u & 0x80000000u) ? ~u : (u | 0x80000000u);
}
__device__ __forceinline__ float decf(unsigned e) {
    unsigned u = (e & 0x80000000u) ? (e & 0x7fffffffu) : ~e;
    return __uint_as_float(u);
}

// K1: ascending rank-sort of preds via counting. 256 blocks x 256 threads.
__global__ void k_rank_preds(const float* __restrict__ preds, float* __restrict__ xs) {
    __shared__ __align__(16) float sp[N];
    __shared__ int part[16][17];
    int tid = threadIdx.x;
    int b = blockIdx.x;
    for (int m = 0; m < 16; m++) sp[tid + 256 * m] = preds[tid + 256 * m];
    __syncthreads();
    int eloc = tid & 15;
    int slice = tid >> 4;
    int i = b * 16 + eloc;
    float v = sp[i];
    int cnt = 0;
    const float4* sp4 = (const float4*)sp;
    for (int it = 0; it < 64; it++) {
        int q = slice * 64 + ((it + slice) & 63); // stagger slices across banks
        float4 a = sp4[q];
        int j = q * 4;
        cnt += (a.x < v) || (a.x == v && (j + 0) < i);
        cnt += (a.y < v) || (a.y == v && (j + 1) < i);
        cnt += (a.z < v) || (a.z == v && (j + 2) < i);
        cnt += (a.w < v) || (a.w == v && (j + 3) < i);
    }
    part[eloc][slice] = cnt;
    __syncthreads();
    if (tid < 16) {
        int r = 0;
        #pragma unroll
        for (int s = 0; s < 16; s++) r += part[tid][s];
        xs[r] = sp[b * 16 + tid];
    }
}

// K2: y[i] = softmax_j(-(xs_i - preds_j)^2/tau) . target   (row max is exactly 0)
__global__ void k_softmax_mv(const float* __restrict__ preds, const float* __restrict__ target,
                             const float* __restrict__ xs, float* __restrict__ y) {
    __shared__ float sp[N];
    __shared__ float st[N];
    __shared__ float rz[4], rn[4];
    int tid = threadIdx.x; // 256
    for (int m = 0; m < 16; m++) {
        int idx = tid + 256 * m;
        sp[idx] = preds[idx];
        st[idx] = target[idx];
    }
    __syncthreads();
    int row0 = blockIdx.x * 8;
    for (int rr = 0; rr < 8; rr++) {
        int i = row0 + rr;
        float xv = xs[i];
        float Z = 0.f, Nm = 0.f;
        #pragma unroll 4
        for (int m = 0; m < 16; m++) {
            int jj = tid + 256 * m;
            float dx = xv - sp[jj];
            float e = __expf(-100.0f * dx * dx);
            Z += e;
            Nm += e * st[jj];
        }
        #pragma unroll
        for (int d = 32; d; d >>= 1) {
            Z += __shfl_down(Z, d);
            Nm += __shfl_down(Nm, d);
        }
        if ((tid & 63) == 0) { rz[tid >> 6] = Z; rn[tid >> 6] = Nm; }
        __syncthreads();
        if (tid == 0) {
            float Zt = rz[0] + rz[1] + rz[2] + rz[3];
            float Nt = rn[0] + rn[1] + rn[2] + rn[3];
            y[i] = Nt / Zt;
        }
        __syncthreads();
    }
}

// K3: descending stable rank-sort of y via counting; s[r]=y*100, perm[r]=i.
//     venc init only used by fallback path (pass nullptr otherwise).
__global__ void k_rank_y(const float* __restrict__ y, float* __restrict__ s_out,
                         int* __restrict__ perm_out, unsigned* __restrict__ venc) {
    __shared__ __align__(16) float sy[N];
    __shared__ int part[16][17];
    int tid = threadIdx.x;
    int b = blockIdx.x;
    for (int m = 0; m < 16; m++) sy[tid + 256 * m] = y[tid + 256 * m];
    __syncthreads();
    int eloc = tid & 15;
    int slice = tid >> 4;
    int i = b * 16 + eloc;
    float v = sy[i];
    int cnt = 0;
    const float4* sy4 = (const float4*)sy;
    for (int it = 0; it < 64; it++) {
        int q = slice * 64 + ((it + slice) & 63);
        float4 a = sy4[q];
        int j = q * 4;
        cnt += (a.x > v) || (a.x == v && (j + 0) < i);
        cnt += (a.y > v) || (a.y == v && (j + 1) < i);
        cnt += (a.z > v) || (a.z == v && (j + 2) < i);
        cnt += (a.w > v) || (a.w == v && (j + 3) < i);
    }
    part[eloc][slice] = cnt;
    __syncthreads();
    if (tid < 16) {
        int r = 0;
        #pragma unroll
        for (int s = 0; s < 16; s++) r += part[tid][s];
        int i2 = b * 16 + tid;
        s_out[r] = sy[i2] * 100.0f;
        perm_out[r] = i2;
        if (venc) venc[i2] = encf(-INFINITY);
    }
}

// K4 (fast): fused per-block f64 cumsum + isotonic min-max scan; writes per-block
// column-max partial P[b][0..N) with plain float4 stores (no atomics).
__global__ void k_iso3(const float* __restrict__ s, float* __restrict__ P) {
    __shared__ __align__(16) float mArr[4][256];
    __shared__ float incl[4][257];
    __shared__ double cj[16];
    __shared__ double wsum[4];
    int tid = threadIdx.x; // 256
    int b = blockIdx.x;
    int j0 = b * 16;
    int kbase = tid * 16;
    int lane = tid & 63, wid = tid >> 6;

    // --- fused f64 cumsum of z[t] = (N - t) - s[t]; loc[e] -> cs[kbase+e+1]
    double loc[16];
    {
        const float4* s4 = (const float4*)s;
        double tot = 0.0;
        #pragma unroll
        for (int q = 0; q < 4; q++) {
            float4 a = s4[tid * 4 + q];
            int t0 = kbase + q * 4;
            tot += (double)(N - (t0 + 0)) - (double)a.x; loc[q * 4 + 0] = tot;
            tot += (double)(N - (t0 + 1)) - (double)a.y; loc[q * 4 + 1] = tot;
            tot += (double)(N - (t0 + 2)) - (double)a.z; loc[q * 4 + 2] = tot;
            tot += (double)(N - (t0 + 3)) - (double)a.w; loc[q * 4 + 3] = tot;
        }
        double w = tot;
        #pragma unroll
        for (int d = 1; d < 64; d <<= 1) {
            double o = __shfl_up(w, d);
            if (lane >= d) w += o;
        }
        if (lane == 63) wsum[wid] = w;
        __syncthreads();
        double base = 0.0;
        #pragma unroll
        for (int q = 0; q < 4; q++) if (q < wid) base += wsum[q];
        double excl = base + (w - tot); // exclusive prefix of this thread
        #pragma unroll
        for (int e = 0; e < 16; e++) loc[e] += excl; // loc[e] = cs[kbase+1+e]
        if (tid == b) { // this thread owns elements [j0, j0+16): cs[j0+m]
            cj[0] = excl;
            #pragma unroll
            for (int m = 1; m < 16; m++) cj[m] = loc[m - 1];
        }
    }
    __syncthreads();

    // --- isotonic min-max: rows j in [j0, j0+16), suffix-min over k, col-max
    float vloc[16];
    #pragma unroll
    for (int e = 0; e < 16; e++) vloc[e] = -INFINITY;
    float ls[4][16];
    for (int grp = 0; grp < 4; grp++) {
        #pragma unroll
        for (int rq = 0; rq < 4; rq++) {
            int j = j0 + grp * 4 + rq;
            double csj = cj[grp * 4 + rq];
            float run = INFINITY;
            #pragma unroll
            for (int e = 15; e >= 0; e--) {
                int k = kbase + e;
                float f = INFINITY;
                if (k >= j) {
                    f = (float)(loc[e] - csj) * __builtin_amdgcn_rcpf((float)(k - j + 1));
                }
                run = fminf(f, run);
                ls[rq][e] = run;
            }
            mArr[rq][tid] = run;
        }
        __syncthreads();
        {
            int w = tid >> 6, l = tid & 63;
            float4 xv = ((const float4*)mArr[w])[l];
            float s3 = xv.w;
            float s2 = fminf(xv.z, s3);
            float s1 = fminf(xv.y, s2);
            float s0 = fminf(xv.x, s1);
            float t = s0;
            #pragma unroll
            for (int d = 1; d < 64; d <<= 1) {
                float o = __shfl_down(t, d);
                if (l + d < 64) t = fminf(t, o);
            }
            float after = __shfl_down(t, 1);
            if (l == 63) after = INFINITY;
            incl[w][4 * l + 0] = fminf(s0, after);
            incl[w][4 * l + 1] = fminf(s1, after);
            incl[w][4 * l + 2] = fminf(s2, after);
            incl[w][4 * l + 3] = fminf(s3, after);
            if (l == 0) incl[w][256] = INFINITY;
        }
        __syncthreads();
        #pragma unroll
        for (int rq = 0; rq < 4; rq++) {
            int j = j0 + grp * 4 + rq;
            float aft = incl[rq][tid + 1];
            #pragma unroll
            for (int e = 0; e < 16; e++) {
                int i = kbase + e;
                float sv = fminf(ls[rq][e], aft);
                if (i >= j) vloc[e] = fmaxf(vloc[e], sv);
            }
        }
        __syncthreads();
    }
    float4* P4 = (float4*)(P + (size_t)b * N);
    #pragma unroll
    for (int q = 0; q < 4; q++)
        P4[tid * 4 + q] = make_float4(vloc[4 * q + 0], vloc[4 * q + 1],
                                      vloc[4 * q + 2], vloc[4 * q + 3]);
}

// K5 (fast): T[i] = max_b P[b][i]; r[perm[i]] = s[i] + T[i]. 256 blocks x 256.
__global__ void k_reduce(const float* __restrict__ P, const float* __restrict__ s,
                         const int* __restrict__ perm, float* __restrict__ r) {
    __shared__ float part[16][17];
    int tid = threadIdx.x;
    int col = tid & 15;       // column within block's 16
    int slice = tid >> 4;     // which 16 b's
    int i = blockIdx.x * 16 + col;
    float m = -INFINITY;
    #pragma unroll
    for (int q = 0; q < 16; q++) {
        int b = slice * 16 + q;
        m = fmaxf(m, P[(size_t)b * N + i]);
    }
    part[col][slice] = m;
    __syncthreads();
    if (tid < 16) {
        float T = -INFINITY;
        #pragma unroll
        for (int q = 0; q < 16; q++) T = fmaxf(T, part[tid][q]);
        int i2 = blockIdx.x * 16 + tid;
        r[perm[i2]] = s[i2] + T;
    }
}

// K6 (fast): diff-sum over r in original order; emit out. 1 block x 256.
__global__ void k_finish2(const float* __restrict__ r, float* __restrict__ out) {
    __shared__ double red[4];
    int tid = threadIdx.x;
    const float4* r4 = (const float4*)r;
    float a[16];
    #pragma unroll
    for (int q = 0; q < 4; q++) {
        float4 x = r4[tid * 4 + q];
        a[q * 4 + 0] = x.x; a[q * 4 + 1] = x.y; a[q * 4 + 2] = x.z; a[q * 4 + 3] = x.w;
    }
    float extra = (tid < 255) ? r[tid * 16 + 16] : 0.0f;
    double acc = 0.0;
    #pragma unroll
    for (int e = 0; e < 16; e++) {
        int d = tid * 16 + e;
        float nxt = (e < 15) ? a[e + 1] : extra;
        if (d < N - 1) acc += fabs((double)nxt - (double)a[e]);
    }
    #pragma unroll
    for (int dd = 32; dd; dd >>= 1) acc += __shfl_down(acc, dd);
    if ((tid & 63) == 0) red[tid >> 6] = acc;
    __syncthreads();
    if (tid == 0) {
        double ds = red[0] + red[1] + red[2] + red[3];
        double xi = 1.0 - 3.0 * ds / ((double)N * (double)N - 1.0);
        out[0] = (float)(-1.0 * xi); // loss = -WEIGHT * xi
        out[1] = (float)xi;
    }
}

// ---------------- fallback path (atomics), proven in round 2 ----------------
__global__ void k_cumsum(const float* __restrict__ s, double* __restrict__ cs) {
    __shared__ double wt[4];
    int tid = threadIdx.x;
    int lane = tid & 63, wid = tid >> 6;
    const float4* s4 = (const float4*)s;
    double loc[16];
    double tot = 0.0;
    #pragma unroll
    for (int q = 0; q < 4; q++) {
        float4 a = s4[tid * 4 + q];
        int t0 = tid * 16 + q * 4;
        tot += (double)(N - (t0 + 0)) - (double)a.x; loc[q * 4 + 0] = tot;
        tot += (double)(N - (t0 + 1)) - (double)a.y; loc[q * 4 + 1] = tot;
        tot += (double)(N - (t0 + 2)) - (double)a.z; loc[q * 4 + 2] = tot;
        tot += (double)(N - (t0 + 3)) - (double)a.w; loc[q * 4 + 3] = tot;
    }
    double w = tot;
    #pragma unroll
    for (int d = 1; d < 64; d <<= 1) {
        double o = __shfl_up(w, d);
        if (lane >= d) w += o;
    }
    if (lane == 63) wt[wid] = w;
    __syncthreads();
    double base = 0.0;
    for (int q = 0; q < 4; q++) if (q < wid) base += wt[q];
    double excl = base + (w - tot);
    #pragma unroll
    for (int e = 0; e < 16; e++) cs[tid * 16 + e + 1] = excl + loc[e];
    if (tid == 0) cs[0] = 0.0;
}

__global__ void k_iso2(const double* __restrict__ cs, unsigned* __restrict__ venc) {
    __shared__ __align__(16) float mArr[4][256];
    __shared__ float incl[4][257];
    __shared__ double cj[16];
    int tid = threadIdx.x;
    int j0 = blockIdx.x * 16;
    int kbase = tid * 16;
    if (tid < 16) cj[tid] = cs[j0 + tid];
    double csr[16];
    #pragma unroll
    for (int e = 0; e < 16; e++) csr[e] = cs[kbase + 1 + e];
    float vloc[16];
    #pragma unroll
    for (int e = 0; e < 16; e++) vloc[e] = -INFINITY;
    __syncthreads();
    float ls[4][16];
    for (int grp = 0; grp < 4; grp++) {
        #pragma unroll
        for (int rq = 0; rq < 4; rq++) {
            int j = j0 + grp * 4 + rq;
            double csj = cj[grp * 4 + rq];
            float run = INFINITY;
            #pragma unroll
            for (int e = 15; e >= 0; e--) {
                int k = kbase + e;
                float f = INFINITY;
                if (k >= j) f = (float)(csr[e] - csj) * __builtin_amdgcn_rcpf((float)(k - j + 1));
                run = fminf(f, run);
                ls[rq][e] = run;
            }
            mArr[rq][tid] = run;
        }
        __syncthreads();
        {
            int w = tid >> 6, l = tid & 63;
            float4 xv = ((const float4*)mArr[w])[l];
            float s3 = xv.w;
            float s2 = fminf(xv.z, s3);
            float s1 = fminf(xv.y, s2);
            float s0 = fminf(xv.x, s1);
            float t = s0;
            #pragma unroll
            for (int d = 1; d < 64; d <<= 1) {
                float o = __shfl_down(t, d);
                if (l + d < 64) t = fminf(t, o);
            }
            float after = __shfl_down(t, 1);
            if (l == 63) after = INFINITY;
            incl[w][4 * l + 0] = fminf(s0, after);
            incl[w][4 * l + 1] = fminf(s1, after);
            incl[w][4 * l + 2] = fminf(s2, after);
            incl[w][4 * l + 3] = fminf(s3, after);
            if (l == 0) incl[w][256] = INFINITY;
        }
        __syncthreads();
        #pragma unroll
        for (int rq = 0; rq < 4; rq++) {
            int j = j0 + grp * 4 + rq;
            float aft = incl[rq][tid + 1];
            #pragma unroll
            for (int e = 0; e < 16; e++) {
                int i = kbase + e;
                float sv = fminf(ls[rq][e], aft);
                if (i >= j) vloc[e] = fmaxf(vloc[e], sv);
            }
        }
        __syncthreads();
    }
    if (kbase + 15 >= j0) {
        #pragma unroll
        for (int e = 0; e < 16; e++) {
            int i = kbase + e;
            if (i >= j0) atomicMax(&venc[i], encf(vloc[e]));
        }
    }
}

__global__ void k_finish(const unsigned* __restrict__ venc, const float* __restrict__ s,
                         const int* __restrict__ perm, float* __restrict__ out) {
    __shared__ float r[N];
    __shared__ double red[16];
    int tid = threadIdx.x; // 1024
    for (int m = 0; m < 4; m++) {
        int t = tid + 1024 * m;
        float u = decf(venc[t]);
        r[perm[t]] = s[t] + u;
    }
    __syncthreads();
    double acc = 0.0;
    for (int m = 0; m < 4; m++) {
        int d = tid + 1024 * m;
        if (d < N - 1) acc += fabs((double)r[d + 1] - (double)r[d]);
    }
    #pragma unroll
    for (int dd = 32; dd; dd >>= 1) acc += __shfl_down(acc, dd);
    if ((tid & 63) == 0) red[tid >> 6] = acc;
    __syncthreads();
    if (tid == 0) {
        double ds = 0.0;
        for (int w = 0; w < 16; w++) ds += red[w];
        double xi = 1.0 - 3.0 * ds / ((double)N * (double)N - 1.0);
        out[0] = (float)(-1.0 * xi);
        out[1] = (float)xi;
    }
}

extern "C" void kernel_launch(void* const* d_in, const int* in_sizes, int n_in,
                              void* d_out, int out_size, void* d_ws, size_t ws_size,
                              hipStream_t stream) {
    const float* preds  = (const float*)d_in[0];
    const float* target = (const float*)d_in[1];
    float* out = (float*)d_out;

    char* ws = (char*)d_ws;
    float*    xs   = (float*)(ws);            // 16 KB
    float*    y    = (float*)(ws + 16384);    // 16 KB
    float*    s    = (float*)(ws + 32768);    // 16 KB
    int*      perm = (int*)(ws + 49152);      // 16 KB
    float*    r    = (float*)(ws + 65536);    // 16 KB (fast) / venc (fallback)
    unsigned* venc = (unsigned*)(ws + 65536);
    double*   cs   = (double*)(ws + 81920);   // 32 KB (fallback)
    float*    P    = (float*)(ws + 81920);    // 4 MB  (fast)

    const size_t need_fast = 81920 + (size_t)256 * N * sizeof(float);
    bool fast = ws_size >= need_fast;

    k_rank_preds<<<256, 256, 0, stream>>>(preds, xs);
    k_softmax_mv<<<512, 256, 0, stream>>>(preds, target, xs, y);
    if (fast) {
        k_rank_y<<<256, 256, 0, stream>>>(y, s, perm, nullptr);
        k_iso3<<<256, 256, 0, stream>>>(s, P);
        k_reduce<<<256, 256, 0, stream>>>(P, s, perm, r);
        k_finish2<<<1, 256, 0, stream>>>(r, out);
    } else {
        k_rank_y<<<256, 256, 0, stream>>>(y, s, perm, venc);
        k_cumsum<<<1, 256, 0, stream>>>(s, cs);
        k_iso2<<<256, 256, 0, stream>>>(cs, venc);
        k_finish<<<1, 1024, 0, stream>>>(venc, s, perm, out);
    }
}